// Round 16
// baseline (292.341 us; speedup 1.0000x reference)
//
#include <hip/hip_runtime.h>
#include <hip/hip_bf16.h>
#include <math.h>

#define BS   8192   // batch*seq tokens
#define SEQQ 2048
#define HID  1024
#define ES   2048   // n_exp * slots
#define FFN  2730
#define FFNP 2752   // FFN padded to multiple of 32
#define NEXP 16
#define SLOT 128

typedef __attribute__((ext_vector_type(4))) float  f32x4;
typedef __attribute__((ext_vector_type(2))) float  f32x2;
typedef __attribute__((ext_vector_type(8))) short  short8;
typedef __attribute__((ext_vector_type(4))) short  short4v;

__device__ __forceinline__ short f2bf(float f) {
    union { float f; unsigned u; } v; v.f = f;
    unsigned r = v.u + 0x7fffu + ((v.u >> 16) & 1u);   // RNE
    return (short)(r >> 16);
}

__device__ __forceinline__ float bf2f(short s) {
    union { unsigned u; float f; } v;
    v.u = ((unsigned)(unsigned short)s) << 16;
    return v.f;
}

// GEMM LDS swizzle (shorts). Row = 32 shorts, slot' = slot ^ ((row>>1)&3).
// Verified conflict-free for frag reads + 16B staging writes (rounds 4-15).
__device__ __forceinline__ int swz(int row, int kk) {
    return (row << 5) + ((((kk >> 3) ^ (row >> 1)) & 3) << 3) + (kk & 7);
}

#define GLD16(gp, lp)                                                   \
    __builtin_amdgcn_global_load_lds(                                   \
        (__attribute__((address_space(1))) void*)(gp),                  \
        (__attribute__((address_space(3))) void*)(lp), 16, 0, 0)

// Transpose-tile swizzle for 64es x 256tok LDS tiles (see round 7).
__device__ __forceinline__ int tsw(int e) { return ((e >> 3) ^ e) & 7; }

// ---------- fused prep: exp(logits) -> DT [ES][BS] + CB [BS][ES] + sum partials ----------
__global__ __launch_bounds__(256) void exp_stats_kernel(const float* __restrict__ L,
                                                        short* __restrict__ DT,
                                                        short* __restrict__ CB,
                                                        float* __restrict__ rowpart,
                                                        float* __restrict__ colpart)
{
    const int t0 = (blockIdx.x & 31) << 8;       // 256-token tile
    const int et = blockIdx.x >> 5;              // es tile 0..31
    const int e0 = et << 6;                      // 64-es tile
    const int tid = threadIdx.x;
    const int lane = tid & 63;
    const int row = tid >> 3;                    // 0..31
    const int seg = tid & 7;                     // 0..7

    __shared__ short T[64 * 256];
    __shared__ float CP[4][64];

    float colacc[8];
    #pragma unroll
    for (int j = 0; j < 8; ++j) colacc[j] = 0.f;

    #pragma unroll
    for (int p = 0; p < 8; ++p) {
        const int tok = p * 32 + row;
        const float* src = L + (size_t)(t0 + tok) * ES + e0 + seg * 8;
        f32x4 a = *reinterpret_cast<const f32x4*>(src);
        f32x4 b = *reinterpret_cast<const f32x4*>(src + 4);
        float ex[8];
        #pragma unroll
        for (int j = 0; j < 4; ++j) ex[j]     = __expf(a[j]);
        #pragma unroll
        for (int j = 0; j < 4; ++j) ex[4 + j] = __expf(b[j]);
        float rs = 0.f;
        #pragma unroll
        for (int j = 0; j < 8; ++j) {
            const int e = seg * 8 + j;
            T[e * 256 + (tok ^ (((seg ^ j) & 7) << 3))] = f2bf(ex[j]);
            colacc[j] += ex[j];
            rs += ex[j];
        }
        rs += __shfl_xor(rs, 1, 64);
        rs += __shfl_xor(rs, 2, 64);
        rs += __shfl_xor(rs, 4, 64);
        if (seg == 0) rowpart[(size_t)(t0 + tok) * 32 + et] = rs;
    }
    #pragma unroll
    for (int j = 0; j < 8; ++j) {
        colacc[j] += __shfl_xor(colacc[j], 8, 64);
        colacc[j] += __shfl_xor(colacc[j], 16, 64);
        colacc[j] += __shfl_xor(colacc[j], 32, 64);
    }
    if ((lane >> 3) == 0) {
        #pragma unroll
        for (int j = 0; j < 8; ++j) CP[tid >> 6][(lane & 7) * 8 + j] = colacc[j];
    }
    __syncthreads();
    if (tid < 64)
        colpart[(size_t)(t0 >> 8) * ES + e0 + tid] =
            CP[0][tid] + CP[1][tid] + CP[2][tid] + CP[3][tid];
    // DT write-out (tok-contiguous 16B chunks per es row)
    {
        const int e = tid >> 2, ts = tid & 3;
        const int sw = tsw(e) << 3;
        const size_t o = (size_t)(e0 + e) * BS + t0 + ts * 64;
        #pragma unroll
        for (int q = 0; q < 8; ++q) {
            short8 w = *reinterpret_cast<const short8*>(&T[e * 256 + ((ts * 64 + q * 8) ^ sw)]);
            *reinterpret_cast<short8*>(&DT[o + q * 8]) = w;
        }
    }
    // CB write-out (es-contiguous 16B chunks per token)
    {
        #pragma unroll
        for (int p = 0; p < 8; ++p) {
            const int tok = p * 32 + row;
            short8 w;
            #pragma unroll
            for (int j = 0; j < 8; ++j) {
                const int e = seg * 8 + j;
                w[j] = T[e * 256 + (tok ^ (((seg ^ j) & 7) << 3))];
            }
            *reinterpret_cast<short8*>(&CB[(size_t)(t0 + tok) * ES + e0 + seg * 8]) = w;
        }
    }
}

__global__ __launch_bounds__(256) void rrow_kernel(const float* __restrict__ rowpart,
                                                   float* __restrict__ crcp)
{
    const int t = blockIdx.x * 256 + threadIdx.x;
    const float* p = rowpart + (size_t)t * 32;
    float s = 0.f;
    #pragma unroll
    for (int j = 0; j < 8; ++j) {
        f32x4 v = *reinterpret_cast<const f32x4*>(p + 4 * j);
        s += (v[0] + v[1]) + (v[2] + v[3]);
    }
    crcp[t] = 1.f / s;
}

__global__ __launch_bounds__(256) void rcol_kernel(const float* __restrict__ colpart,
                                                   float* __restrict__ drcp)
{
    const int g = blockIdx.x * 256 + threadIdx.x;   // b*2048 + c
    const int b = g >> 11, c = g & 2047;
    float s = 0.f;
    #pragma unroll
    for (int ch = 0; ch < 8; ++ch)
        s += colpart[(size_t)(b * 8 + ch) * ES + c];
    drcp[g] = 1.f / s;
}

// ---------- x fp32 [8192][1024] -> xT bf16 [1024][8192] ----------
__global__ __launch_bounds__(256) void transpose_x(const float* __restrict__ X,
                                                   short* __restrict__ XT)
{
    __shared__ short T[64][72];
    const int tid = threadIdx.x;
    const int k0 = blockIdx.x * 64;
    const int n0 = blockIdx.y * 64;
    {
        const int kk = tid >> 2;
        const int nn = (tid & 3) * 16;
        const float* src = X + (size_t)(k0 + kk) * HID + n0 + nn;
        #pragma unroll
        for (int j = 0; j < 4; ++j) {
            f32x4 v = *reinterpret_cast<const f32x4*>(src + 4 * j);
            short4v s;
            #pragma unroll
            for (int i = 0; i < 4; ++i) s[i] = f2bf(v[i]);
            *reinterpret_cast<short4v*>(&T[kk][nn + 4 * j]) = s;
        }
    }
    __syncthreads();
    {
        const int nn  = tid >> 2;
        const int kk4 = (tid & 3) * 16;
        short8 w0, w1;
        #pragma unroll
        for (int i = 0; i < 8; ++i) w0[i] = T[kk4 + i][nn];
        #pragma unroll
        for (int i = 0; i < 8; ++i) w1[i] = T[kk4 + 8 + i][nn];
        size_t o = (size_t)(n0 + nn) * BS + k0 + kk4;
        *reinterpret_cast<short8*>(&XT[o])     = w0;
        *reinterpret_cast<short8*>(&XT[o + 8]) = w1;
    }
}

// ---------- xt = bf16(sum_z drcp[z][c] * part_bf16[z][c][h]) (z = batch, 4 splits) ----------
__global__ __launch_bounds__(256) void reduce_xt(const short* __restrict__ P,
                                                 const float* __restrict__ drcp,
                                                 short* __restrict__ xt)
{
    const size_t i = ((size_t)blockIdx.x * 256 + threadIdx.x) * 4;
    const int c = (int)(i >> 10);
    const size_t CH = (size_t)ES * HID;
    short4v s0 = *reinterpret_cast<const short4v*>(&P[i]);
    short4v s1 = *reinterpret_cast<const short4v*>(&P[i + CH]);
    short4v s2 = *reinterpret_cast<const short4v*>(&P[i + 2 * CH]);
    short4v s3 = *reinterpret_cast<const short4v*>(&P[i + 3 * CH]);
    const float r0 = drcp[c], r1 = drcp[ES + c], r2 = drcp[2 * ES + c], r3 = drcp[3 * ES + c];
    short4v o;
    #pragma unroll
    for (int j = 0; j < 4; ++j)
        o[j] = f2bf((bf2f(s0[j]) * r0 + bf2f(s1[j]) * r1) +
                    (bf2f(s2[j]) * r2 + bf2f(s3[j]) * r3));
    *reinterpret_cast<short4v*>(&xt[i]) = o;
}

// ---------------- bf16 MFMA GEMM body ----------------
// BT path: TRIPLE-buffered gload_lds + counted vmcnt(4) raw barriers — next-next
//   tile's 4 loads stay in flight across each barrier (T4: never drain to 0).
// float-B path (FW=4): f32x4 weight loads + counted-vmcnt raw barriers (round 14).
// EPI: 0 none, 1 silu, 2 row-scale by aux[m].
// PADW: store n >= Ndim too (acc==0 there since B staged 0).
template<int BM, int BN, int EPI, bool NBND, bool KBND, bool BT, bool CT, bool PADW,
         int FW, typename TB, typename TC>
__device__ __forceinline__
void gemm_body(const short* __restrict__ A, const TB* __restrict__ B,
               TC* __restrict__ C, int Ndim, int Kdim,
               int lda, int ldb, int ldc,
               long sA, long sB, long sC, const float* __restrict__ aux)
{
    constexpr int BK = 32;
    A += (size_t)blockIdx.z * sA;
    B += (size_t)blockIdx.z * sB;
    C += (size_t)blockIdx.z * sC;
    const int m0 = blockIdx.x * BM;
    const int n0 = blockIdx.y * BN;
    const int tid  = threadIdx.x;
    const int lane = tid & 63;
    const int wid  = tid >> 6;
    const int wm = wid >> 1, wn = wid & 1;
    constexpr int WMT = BM / 2, WNT = BN / 2, MI = WMT / 16, NI = WNT / 16;
    constexpr int PA = BM / 64;
    constexpr int PB = BN / 64;

    __shared__ __align__(16) short As0[BM * 32], As1[BM * 32];
    __shared__ __align__(16) short Bs0[BN * 32], Bs1[BN * 32];
    __shared__ __align__(16) short As2[BT ? BM * 32 : 8];
    __shared__ __align__(16) short Bs2[BT ? BN * 32 : 8];

    f32x4 acc[MI][NI];
    #pragma unroll
    for (int mi = 0; mi < MI; ++mi)
        #pragma unroll
        for (int ni = 0; ni < NI; ++ni)
            acc[mi][ni] = (f32x4){0.f, 0.f, 0.f, 0.f};

    // float-B lane geometry (FW==4): 4 n x 2 k per thread
    const int fn = (tid & 15) * 4;
    const int fk = (tid >> 4) * 2;

    // issue direct-to-LDS loads for A (and B when BT): PA+PB gload_lds per wave
    auto ISSUEA = [&](short* ASP, short* BSP, int kk) {
        #pragma unroll
        for (int p = 0; p < PA; ++p) {
            const int slot = p * 256 + tid;
            const int row  = slot >> 2;
            const int seg  = (slot & 3) ^ ((row >> 1) & 3);
            GLD16(&A[(size_t)(m0 + row) * lda + kk + seg * 8],
                  &ASP[(p * 256 + wid * 64) * 8]);
        }
        if constexpr (BT) {
            #pragma unroll
            for (int p = 0; p < PB; ++p) {
                const int slot = p * 256 + tid;
                const int row  = slot >> 2;
                const int seg  = (slot & 3) ^ ((row >> 1) & 3);
                GLD16(&B[(size_t)(n0 + row) * ldb + kk + seg * 8],
                      &BSP[(p * 256 + wid * 64) * 8]);
            }
        }
    };

    // float-B: 2x f32x4 into named regs. NBND tail: per-element guarded loads.
    auto LOADB = [&](f32x4* bF, int kk) {
        const int n_ = n0 + fn;
        #pragma unroll
        for (int r = 0; r < 2; ++r) {
            const int k_ = kk + fk + r;
            const bool okk = (!KBND) || (k_ < Kdim);
            if constexpr (NBND) {
                if (okk && (n_ + 3 < Ndim)) {
                    bF[r] = *reinterpret_cast<const f32x4*>(&B[(size_t)k_ * ldb + n_]);
                } else {
                    #pragma unroll
                    for (int i = 0; i < 4; ++i)
                        bF[r][i] = (okk && (n_ + i < Ndim))
                                       ? B[(size_t)k_ * ldb + n_ + i] : 0.f;
                }
            } else {
                bF[r] = okk ? *reinterpret_cast<const f32x4*>(&B[(size_t)k_ * ldb + n_])
                            : (f32x4){0.f, 0.f, 0.f, 0.f};
            }
        }
    };

    auto PACKB = [&](short* BSP, const f32x4* bF) {
        #pragma unroll
        for (int i = 0; i < 4; ++i) {
            unsigned lo = (unsigned short)f2bf(bF[0][i]);
            unsigned hi = (unsigned short)f2bf(bF[1][i]);
            *reinterpret_cast<unsigned*>(&BSP[swz(fn + i, fk)]) = lo | (hi << 16);
        }
    };

    auto COMPUTE = [&](const short* ASP, const short* BSP) {
        const int ar = lane & 15;
        const int ac = (lane >> 4) * 8;
        short8 af[MI], bf[NI];
        #pragma unroll
        for (int mi = 0; mi < MI; ++mi)
            af[mi] = *reinterpret_cast<const short8*>(&ASP[swz(wm * WMT + mi * 16 + ar, ac)]);
        #pragma unroll
        for (int ni = 0; ni < NI; ++ni)
            bf[ni] = *reinterpret_cast<const short8*>(&BSP[swz(wn * WNT + ni * 16 + ar, ac)]);
        #pragma unroll
        for (int mi = 0; mi < MI; ++mi)
            #pragma unroll
            for (int ni = 0; ni < NI; ++ni)
                acc[mi][ni] = __builtin_amdgcn_mfma_f32_16x16x32_bf16(
                    af[mi], bf[ni], acc[mi][ni], 0, 0, 0);
    };

    const int Kloop = KBND ? ((Kdim + 31) & ~31) : Kdim;
    const int nt = Kloop / BK;   // >= 2 (even for the float-B path)

    if constexpr (BT) {
        static_assert(!BT || (PA + PB == 4), "vmcnt literal assumes 4 loads/wave/tile");
        // triple-buffer rotation: compute cur, tile t+1 landing in nxt (loads
        // issued last phase, guaranteed complete at the barrier via vmcnt(4)),
        // tile t+2 streaming into nx2 (its 4 loads stay in flight across the
        // barrier — never drained to 0 in steady state).
        short *Ac = As0, *An = As1, *Ax = As2;
        short *Bc = Bs0, *Bn = Bs1, *Bx = Bs2;
        ISSUEA(Ac, Bc, 0);
        ISSUEA(An, Bn, BK);
        asm volatile("s_waitcnt vmcnt(4) lgkmcnt(0)" ::: "memory");
        __builtin_amdgcn_s_barrier();
        for (int t = 0; t < nt; ++t) {
            const bool p2 = (t + 2 < nt);
            if (p2) ISSUEA(Ax, Bx, (t + 2) * BK);
            COMPUTE(Ac, Bc);
            if (t + 1 < nt) {
                if (p2) asm volatile("s_waitcnt vmcnt(4) lgkmcnt(0)" ::: "memory");
                else    asm volatile("s_waitcnt vmcnt(0) lgkmcnt(0)" ::: "memory");
                __builtin_amdgcn_s_barrier();
            }
            short* tA = Ac; Ac = An; An = Ax; Ax = tA;
            short* tB = Bc; Bc = Bn; Bn = Bx; Bx = tB;
        }
    } else {
        // counted-vmcnt raw-barrier schedule (round 14); only next-tile B loads
        // (2, or more in the divergent NBND tail — over-waiting safe) in flight.
        f32x4 bFa[2], bFb[2];
        LOADB(bFa, 0);
        __builtin_amdgcn_sched_barrier(0);
        ISSUEA(As0, Bs0, 0);
        __builtin_amdgcn_sched_barrier(0);
        LOADB(bFb, BK);
        PACKB(Bs0, bFa);
        asm volatile("s_waitcnt vmcnt(2) lgkmcnt(0)" ::: "memory");
        __builtin_amdgcn_s_barrier();

        for (int t = 0; t < nt; t += 2) {
            {
                ISSUEA(As1, Bs1, (t + 1) * BK);
                __builtin_amdgcn_sched_barrier(0);
                const bool pf = (t + 2 < nt);
                if (pf) LOADB(bFa, (t + 2) * BK);
                COMPUTE(As0, Bs0);
                PACKB(Bs1, bFb);
                if (pf) asm volatile("s_waitcnt vmcnt(2) lgkmcnt(0)" ::: "memory");
                else    asm volatile("s_waitcnt vmcnt(0) lgkmcnt(0)" ::: "memory");
                __builtin_amdgcn_s_barrier();
            }
            {
                const bool p2 = (t + 2 < nt);
                const bool p3 = (t + 3 < nt);
                if (p2) ISSUEA(As0, Bs0, (t + 2) * BK);
                __builtin_amdgcn_sched_barrier(0);
                if (p3) LOADB(bFb, (t + 3) * BK);
                COMPUTE(As1, Bs1);
                if (p2) PACKB(Bs0, bFa);
                if (p3) asm volatile("s_waitcnt vmcnt(2) lgkmcnt(0)" ::: "memory");
                else    asm volatile("s_waitcnt vmcnt(0) lgkmcnt(0)" ::: "memory");
                __builtin_amdgcn_s_barrier();
            }
        }
    }

    #pragma unroll
    for (int mi = 0; mi < MI; ++mi) {
        #pragma unroll
        for (int ni = 0; ni < NI; ++ni) {
            const int n = n0 + wn * WNT + ni * 16 + (lane & 15);
            if (NBND && !PADW && n >= Ndim) continue;
            const int mbase = m0 + wm * WMT + mi * 16 + (lane >> 4) * 4;
            if constexpr (CT) {
                short4v sv;
                #pragma unroll
                for (int r = 0; r < 4; ++r) sv[r] = f2bf(acc[mi][ni][r]);
                *reinterpret_cast<short4v*>(&C[(size_t)n * ldc + mbase]) = sv;
            } else {
                #pragma unroll
                for (int r = 0; r < 4; ++r) {
                    float v = acc[mi][ni][r];
                    if (EPI == 1)      v = v / (1.f + __expf(-v));   // silu
                    else if (EPI == 2) v = v * aux[mbase + r];       // crcp
                    if constexpr (sizeof(TC) == 2) C[(size_t)(mbase + r) * ldc + n] = f2bf(v);
                    else                           C[(size_t)(mbase + r) * ldc + n] = v;
                }
            }
        }
    }
}

// ---------------- named GEMM wrappers (round-8 tiles/grids) ----------------
__global__ __launch_bounds__(256) void g1_gemm(const short* A, const short* B, short* C) {
    gemm_body<128, 128, 0, false, false, true, false, false, 0, short, short>(
        A, B, C, HID, 2048, BS, BS, HID, 2048L, 2048L, (long)ES * HID, nullptr);
}
__global__ __launch_bounds__(256) void g1f_gemm(const short* A, const float* B, short* C) {
    gemm_body<128, 64, 0, false, false, false, false, false, 4, float, short>(
        A, B, C, HID, 2048, BS, HID, HID, 2048L, 2048L * HID, (long)ES * HID, nullptr);
}
__global__ __launch_bounds__(256) void g2_gemm(const short* A, const float* B, short* C) {
    gemm_body<128, 64, 1, true, false, false, false, true, 4, float, short>(
        A, B, C, FFN, HID, HID, FFN, FFNP,
        (long)SLOT * HID, (long)HID * FFN, (long)SLOT * FFNP, nullptr);
}
__global__ __launch_bounds__(256) void g3_gemm(const short* A, const float* B, short* C) {
    gemm_body<64, 64, 0, false, true, false, true, false, 4, float, short>(
        A, B, C, HID, FFN, FFNP, HID, ES,
        (long)SLOT * FFNP, (long)FFN * HID, (long)SLOT, nullptr);
}
__global__ __launch_bounds__(256) void g4_gemm(const short* A, const short* B, float* C,
                                               const float* crcp) {
    gemm_body<128, 128, 2, false, false, true, false, false, 0, short, float>(
        A, B, C, HID, ES, ES, ES, HID, 0, 0, 0, crcp);
}

// ---------------- launch ----------------

extern "C" void kernel_launch(void* const* d_in, const int* in_sizes, int n_in,
                              void* d_out, int out_size, void* d_ws, size_t ws_size,
                              hipStream_t stream)
{
    const float* x      = (const float*)d_in[0];
    const float* logits = (const float*)d_in[1];   // [BS][ES]
    const float* w_up   = (const float*)d_in[2];   // [16][1024][2730]
    const float* w_down = (const float*)d_in[3];   // [16][2730][1024]
    float* y = (float*)d_out;

    float* wsf     = (float*)d_ws;
    float* drcp    = wsf;                               // 4*2048
    float* crcp    = wsf + 8192;                        // 8192
    float* rowpart = wsf + 16384;                       // 8192*32
    float* colpart = rowpart + (size_t)8192 * 32;       // 32*2048
    short* DT      = (short*)(colpart + (size_t)32 * 2048);  // [2048][8192] bf16
    short* CB      = DT + (size_t)ES * BS;              // [8192][2048] bf16
    short* part    = CB + (size_t)BS * ES;              // [4][2048][1024] bf16
    short* xt      = part + (size_t)4 * ES * HID;       // [2048][1024] bf16
    short* h       = xt + (size_t)ES * HID;             // [16][128][2752] bf16
    short* eoutT   = h + (size_t)NEXP * SLOT * FFNP;    // [1024][2048] bf16
    short* xT      = eoutT + (size_t)HID * ES;          // [1024][8192] bf16
    const size_t need_full = (size_t)((char*)(xT + (size_t)HID * BS) - (char*)d_ws);
    const bool use_bt = ws_size >= need_full;

    // NOTE: no memset. h pad columns (2730..2751) written as exact zeros by g2 (PADW).

    exp_stats_kernel<<<1024, 256, 0, stream>>>(logits, DT, CB, rowpart, colpart);
    rrow_kernel<<<32, 256, 0, stream>>>(rowpart, crcp);
    rcol_kernel<<<32, 256, 0, stream>>>(colpart, drcp);

    // G1: part[z] = expDT[:, batch z] @ x[batch z]   (K-split = batch x4, nt=64)
    if (use_bt) {
        transpose_x<<<dim3(128, 16, 1), 256, 0, stream>>>(x, xT);
        g1_gemm<<<dim3(16, 8, 4), 256, 0, stream>>>(DT, xT, part);
    } else {
        g1f_gemm<<<dim3(16, 16, 4), 256, 0, stream>>>(DT, x, part);
    }

    // xt = bf16(sum_z drcp[z] * part[z])
    reduce_xt<<<2048, 256, 0, stream>>>(part, drcp, xt);

    // G2: h[e] = silu(xt_e @ w_up_e), pad cols written as 0   (nt=32, f32x4 B loads)
    g2_gemm<<<dim3(1, 43, NEXP), 256, 0, stream>>>(xt, w_up, h);

    // G3: eoutT = (h_e @ w_down_e)^T   (nt=86, f32x4 B loads)
    g3_gemm<<<dim3(2, 16, NEXP), 256, 0, stream>>>(h, w_down, eoutT);

    // G4: y = expCB @ eout, row-scaled by crcp   (nt=64)
    g4_gemm<<<dim3(64, 8, 1), 256, 0, stream>>>(CB, eoutT, y, crcp);
}

// Round 17
// 287.704 us; speedup vs baseline: 1.0161x; 1.0161x over previous
//
#include <hip/hip_runtime.h>
#include <hip/hip_bf16.h>
#include <math.h>

#define BS   8192   // batch*seq tokens
#define SEQQ 2048
#define HID  1024
#define ES   2048   // n_exp * slots
#define FFN  2730
#define FFNP 2752   // FFN padded to multiple of 32
#define NEXP 16
#define SLOT 128

typedef __attribute__((ext_vector_type(4))) float  f32x4;
typedef __attribute__((ext_vector_type(2))) float  f32x2;
typedef __attribute__((ext_vector_type(8))) short  short8;
typedef __attribute__((ext_vector_type(4))) short  short4v;

__device__ __forceinline__ short f2bf(float f) {
    union { float f; unsigned u; } v; v.f = f;
    unsigned r = v.u + 0x7fffu + ((v.u >> 16) & 1u);   // RNE
    return (short)(r >> 16);
}

__device__ __forceinline__ float bf2f(short s) {
    union { unsigned u; float f; } v;
    v.u = ((unsigned)(unsigned short)s) << 16;
    return v.f;
}

// GEMM LDS swizzle (shorts). Row = 32 shorts, slot' = slot ^ ((row>>1)&3).
// Verified conflict-free for frag reads + 16B staging writes (rounds 4-16).
__device__ __forceinline__ int swz(int row, int kk) {
    return (row << 5) + ((((kk >> 3) ^ (row >> 1)) & 3) << 3) + (kk & 7);
}

#define GLD16(gp, lp)                                                   \
    __builtin_amdgcn_global_load_lds(                                   \
        (__attribute__((address_space(1))) void*)(gp),                  \
        (__attribute__((address_space(3))) void*)(lp), 16, 0, 0)

// Transpose-tile swizzle for 64es x 256tok LDS tiles (see round 7).
__device__ __forceinline__ int tsw(int e) { return ((e >> 3) ^ e) & 7; }

// ---------- fused prep: exp(logits) -> DT [ES][BS] + CB [BS][ES] + sum partials ----------
__global__ __launch_bounds__(256) void exp_stats_kernel(const float* __restrict__ L,
                                                        short* __restrict__ DT,
                                                        short* __restrict__ CB,
                                                        float* __restrict__ rowpart,
                                                        float* __restrict__ colpart)
{
    const int t0 = (blockIdx.x & 31) << 8;       // 256-token tile
    const int et = blockIdx.x >> 5;              // es tile 0..31
    const int e0 = et << 6;                      // 64-es tile
    const int tid = threadIdx.x;
    const int lane = tid & 63;
    const int row = tid >> 3;                    // 0..31
    const int seg = tid & 7;                     // 0..7

    __shared__ short T[64 * 256];
    __shared__ float CP[4][64];

    float colacc[8];
    #pragma unroll
    for (int j = 0; j < 8; ++j) colacc[j] = 0.f;

    #pragma unroll
    for (int p = 0; p < 8; ++p) {
        const int tok = p * 32 + row;
        const float* src = L + (size_t)(t0 + tok) * ES + e0 + seg * 8;
        f32x4 a = *reinterpret_cast<const f32x4*>(src);
        f32x4 b = *reinterpret_cast<const f32x4*>(src + 4);
        float ex[8];
        #pragma unroll
        for (int j = 0; j < 4; ++j) ex[j]     = __expf(a[j]);
        #pragma unroll
        for (int j = 0; j < 4; ++j) ex[4 + j] = __expf(b[j]);
        float rs = 0.f;
        #pragma unroll
        for (int j = 0; j < 8; ++j) {
            const int e = seg * 8 + j;
            T[e * 256 + (tok ^ (((seg ^ j) & 7) << 3))] = f2bf(ex[j]);
            colacc[j] += ex[j];
            rs += ex[j];
        }
        rs += __shfl_xor(rs, 1, 64);
        rs += __shfl_xor(rs, 2, 64);
        rs += __shfl_xor(rs, 4, 64);
        if (seg == 0) rowpart[(size_t)(t0 + tok) * 32 + et] = rs;
    }
    #pragma unroll
    for (int j = 0; j < 8; ++j) {
        colacc[j] += __shfl_xor(colacc[j], 8, 64);
        colacc[j] += __shfl_xor(colacc[j], 16, 64);
        colacc[j] += __shfl_xor(colacc[j], 32, 64);
    }
    if ((lane >> 3) == 0) {
        #pragma unroll
        for (int j = 0; j < 8; ++j) CP[tid >> 6][(lane & 7) * 8 + j] = colacc[j];
    }
    __syncthreads();
    if (tid < 64)
        colpart[(size_t)(t0 >> 8) * ES + e0 + tid] =
            CP[0][tid] + CP[1][tid] + CP[2][tid] + CP[3][tid];
    // DT write-out (tok-contiguous 16B chunks per es row)
    {
        const int e = tid >> 2, ts = tid & 3;
        const int sw = tsw(e) << 3;
        const size_t o = (size_t)(e0 + e) * BS + t0 + ts * 64;
        #pragma unroll
        for (int q = 0; q < 8; ++q) {
            short8 w = *reinterpret_cast<const short8*>(&T[e * 256 + ((ts * 64 + q * 8) ^ sw)]);
            *reinterpret_cast<short8*>(&DT[o + q * 8]) = w;
        }
    }
    // CB write-out (es-contiguous 16B chunks per token)
    {
        #pragma unroll
        for (int p = 0; p < 8; ++p) {
            const int tok = p * 32 + row;
            short8 w;
            #pragma unroll
            for (int j = 0; j < 8; ++j) {
                const int e = seg * 8 + j;
                w[j] = T[e * 256 + (tok ^ (((seg ^ j) & 7) << 3))];
            }
            *reinterpret_cast<short8*>(&CB[(size_t)(t0 + tok) * ES + e0 + seg * 8]) = w;
        }
    }
}

__global__ __launch_bounds__(256) void rrow_kernel(const float* __restrict__ rowpart,
                                                   float* __restrict__ crcp)
{
    const int t = blockIdx.x * 256 + threadIdx.x;
    const float* p = rowpart + (size_t)t * 32;
    float s = 0.f;
    #pragma unroll
    for (int j = 0; j < 8; ++j) {
        f32x4 v = *reinterpret_cast<const f32x4*>(p + 4 * j);
        s += (v[0] + v[1]) + (v[2] + v[3]);
    }
    crcp[t] = 1.f / s;
}

__global__ __launch_bounds__(256) void rcol_kernel(const float* __restrict__ colpart,
                                                   float* __restrict__ drcp)
{
    const int g = blockIdx.x * 256 + threadIdx.x;   // b*2048 + c
    const int b = g >> 11, c = g & 2047;
    float s = 0.f;
    #pragma unroll
    for (int ch = 0; ch < 8; ++ch)
        s += colpart[(size_t)(b * 8 + ch) * ES + c];
    drcp[g] = 1.f / s;
}

// ---------- x fp32 [8192][1024] -> xT bf16 [1024][8192] ----------
__global__ __launch_bounds__(256) void transpose_x(const float* __restrict__ X,
                                                   short* __restrict__ XT)
{
    __shared__ short T[64][72];
    const int tid = threadIdx.x;
    const int k0 = blockIdx.x * 64;
    const int n0 = blockIdx.y * 64;
    {
        const int kk = tid >> 2;
        const int nn = (tid & 3) * 16;
        const float* src = X + (size_t)(k0 + kk) * HID + n0 + nn;
        #pragma unroll
        for (int j = 0; j < 4; ++j) {
            f32x4 v = *reinterpret_cast<const f32x4*>(src + 4 * j);
            short4v s;
            #pragma unroll
            for (int i = 0; i < 4; ++i) s[i] = f2bf(v[i]);
            *reinterpret_cast<short4v*>(&T[kk][nn + 4 * j]) = s;
        }
    }
    __syncthreads();
    {
        const int nn  = tid >> 2;
        const int kk4 = (tid & 3) * 16;
        short8 w0, w1;
        #pragma unroll
        for (int i = 0; i < 8; ++i) w0[i] = T[kk4 + i][nn];
        #pragma unroll
        for (int i = 0; i < 8; ++i) w1[i] = T[kk4 + 8 + i][nn];
        size_t o = (size_t)(n0 + nn) * BS + k0 + kk4;
        *reinterpret_cast<short8*>(&XT[o])     = w0;
        *reinterpret_cast<short8*>(&XT[o + 8]) = w1;
    }
}

// ---------- xt = bf16(sum_z drcp[z][c] * part_bf16[z][c][h]) (z = batch, 4 splits) ----------
__global__ __launch_bounds__(256) void reduce_xt(const short* __restrict__ P,
                                                 const float* __restrict__ drcp,
                                                 short* __restrict__ xt)
{
    const size_t i = ((size_t)blockIdx.x * 256 + threadIdx.x) * 4;
    const int c = (int)(i >> 10);
    const size_t CH = (size_t)ES * HID;
    short4v s0 = *reinterpret_cast<const short4v*>(&P[i]);
    short4v s1 = *reinterpret_cast<const short4v*>(&P[i + CH]);
    short4v s2 = *reinterpret_cast<const short4v*>(&P[i + 2 * CH]);
    short4v s3 = *reinterpret_cast<const short4v*>(&P[i + 3 * CH]);
    const float r0 = drcp[c], r1 = drcp[ES + c], r2 = drcp[2 * ES + c], r3 = drcp[3 * ES + c];
    short4v o;
    #pragma unroll
    for (int j = 0; j < 4; ++j)
        o[j] = f2bf((bf2f(s0[j]) * r0 + bf2f(s1[j]) * r1) +
                    (bf2f(s2[j]) * r2 + bf2f(s3[j]) * r3));
    *reinterpret_cast<short4v*>(&xt[i]) = o;
}

// ---------------- bf16 MFMA GEMM body ----------------
// BT path: gload_lds A+B dbuf with BK=64 MACRO-STEPS (two 32-k sub-tiles per
//   buffer/barrier) — halves barrier-drain count at zero occupancy cost (grid
//   already limits to 2 blocks/CU). #32-k steps must be divisible by 4.
// float-B path (FW=4): f32x4 weight loads + counted-vmcnt raw barriers (round 14).
// EPI: 0 none, 1 silu, 2 row-scale by aux[m].
// PADW: store n >= Ndim too (acc==0 there since B staged 0).
template<int BM, int BN, int EPI, bool NBND, bool KBND, bool BT, bool CT, bool PADW,
         int FW, typename TB, typename TC>
__device__ __forceinline__
void gemm_body(const short* __restrict__ A, const TB* __restrict__ B,
               TC* __restrict__ C, int Ndim, int Kdim,
               int lda, int ldb, int ldc,
               long sA, long sB, long sC, const float* __restrict__ aux)
{
    constexpr int BK = 32;
    constexpr int HB = BT ? 2 : 1;            // k-halves per buffer
    A += (size_t)blockIdx.z * sA;
    B += (size_t)blockIdx.z * sB;
    C += (size_t)blockIdx.z * sC;
    const int m0 = blockIdx.x * BM;
    const int n0 = blockIdx.y * BN;
    const int tid  = threadIdx.x;
    const int lane = tid & 63;
    const int wid  = tid >> 6;
    const int wm = wid >> 1, wn = wid & 1;
    constexpr int WMT = BM / 2, WNT = BN / 2, MI = WMT / 16, NI = WNT / 16;
    constexpr int PA = BM / 64;
    constexpr int PB = BN / 64;

    __shared__ __align__(16) short As0[BM * 32 * HB], As1[BM * 32 * HB];
    __shared__ __align__(16) short Bs0[BN * 32 * HB], Bs1[BN * 32 * HB];

    f32x4 acc[MI][NI];
    #pragma unroll
    for (int mi = 0; mi < MI; ++mi)
        #pragma unroll
        for (int ni = 0; ni < NI; ++ni)
            acc[mi][ni] = (f32x4){0.f, 0.f, 0.f, 0.f};

    // float-B lane geometry (FW==4): 4 n x 2 k per thread
    const int fn = (tid & 15) * 4;
    const int fk = (tid >> 4) * 2;

    // issue direct-to-LDS loads for one 32-k sub-tile of A (and B when BT)
    auto ISSUEA = [&](short* ASP, short* BSP, int kk) {
        #pragma unroll
        for (int p = 0; p < PA; ++p) {
            const int slot = p * 256 + tid;
            const int row  = slot >> 2;
            const int seg  = (slot & 3) ^ ((row >> 1) & 3);
            GLD16(&A[(size_t)(m0 + row) * lda + kk + seg * 8],
                  &ASP[(p * 256 + wid * 64) * 8]);
        }
        if constexpr (BT) {
            #pragma unroll
            for (int p = 0; p < PB; ++p) {
                const int slot = p * 256 + tid;
                const int row  = slot >> 2;
                const int seg  = (slot & 3) ^ ((row >> 1) & 3);
                GLD16(&B[(size_t)(n0 + row) * ldb + kk + seg * 8],
                      &BSP[(p * 256 + wid * 64) * 8]);
            }
        }
    };

    // float-B: 2x f32x4 into named regs. NBND tail: per-element guarded loads.
    auto LOADB = [&](f32x4* bF, int kk) {
        const int n_ = n0 + fn;
        #pragma unroll
        for (int r = 0; r < 2; ++r) {
            const int k_ = kk + fk + r;
            const bool okk = (!KBND) || (k_ < Kdim);
            if constexpr (NBND) {
                if (okk && (n_ + 3 < Ndim)) {
                    bF[r] = *reinterpret_cast<const f32x4*>(&B[(size_t)k_ * ldb + n_]);
                } else {
                    #pragma unroll
                    for (int i = 0; i < 4; ++i)
                        bF[r][i] = (okk && (n_ + i < Ndim))
                                       ? B[(size_t)k_ * ldb + n_ + i] : 0.f;
                }
            } else {
                bF[r] = okk ? *reinterpret_cast<const f32x4*>(&B[(size_t)k_ * ldb + n_])
                            : (f32x4){0.f, 0.f, 0.f, 0.f};
            }
        }
    };

    auto PACKB = [&](short* BSP, const f32x4* bF) {
        #pragma unroll
        for (int i = 0; i < 4; ++i) {
            unsigned lo = (unsigned short)f2bf(bF[0][i]);
            unsigned hi = (unsigned short)f2bf(bF[1][i]);
            *reinterpret_cast<unsigned*>(&BSP[swz(fn + i, fk)]) = lo | (hi << 16);
        }
    };

    auto COMPUTE = [&](const short* ASP, const short* BSP) {
        const int ar = lane & 15;
        const int ac = (lane >> 4) * 8;
        short8 af[MI], bf[NI];
        #pragma unroll
        for (int mi = 0; mi < MI; ++mi)
            af[mi] = *reinterpret_cast<const short8*>(&ASP[swz(wm * WMT + mi * 16 + ar, ac)]);
        #pragma unroll
        for (int ni = 0; ni < NI; ++ni)
            bf[ni] = *reinterpret_cast<const short8*>(&BSP[swz(wn * WNT + ni * 16 + ar, ac)]);
        #pragma unroll
        for (int mi = 0; mi < MI; ++mi)
            #pragma unroll
            for (int ni = 0; ni < NI; ++ni)
                acc[mi][ni] = __builtin_amdgcn_mfma_f32_16x16x32_bf16(
                    af[mi], bf[ni], acc[mi][ni], 0, 0, 0);
    };

    const int Kloop = KBND ? ((Kdim + 31) & ~31) : Kdim;
    const int nt = Kloop / BK;

    if constexpr (BT) {
        // BK=64 macro-steps: each buffer holds two 32-k sub-tiles; one barrier
        // per 64 k. nt must be divisible by 4 (g1/g4: nt=64). Round-8 dbuf flow.
        const int nt2 = nt / 2;
        auto ISSUE2 = [&](short* ASP, short* BSP, int T) {
            ISSUEA(ASP, BSP, T * 64);
            ISSUEA(ASP + BM * 32, BSP + BN * 32, T * 64 + 32);
        };
        auto COMPUTE2 = [&](const short* ASP, const short* BSP) {
            COMPUTE(ASP, BSP);
            COMPUTE(ASP + BM * 32, BSP + BN * 32);
        };
        ISSUE2(As0, Bs0, 0);
        __syncthreads();
        for (int t = 0; t < nt2; t += 2) {
            ISSUE2(As1, Bs1, t + 1);           // t+1 < nt2 (nt2 even)
            COMPUTE2(As0, Bs0);
            __syncthreads();
            const bool p2 = (t + 2 < nt2);
            if (p2) ISSUE2(As0, Bs0, t + 2);
            COMPUTE2(As1, Bs1);
            __syncthreads();
        }
    } else {
        // counted-vmcnt raw-barrier schedule (round 14); only next-tile B loads
        // (2, or more in the divergent NBND tail — over-waiting safe) in flight.
        f32x4 bFa[2], bFb[2];
        LOADB(bFa, 0);
        __builtin_amdgcn_sched_barrier(0);
        ISSUEA(As0, Bs0, 0);
        __builtin_amdgcn_sched_barrier(0);
        LOADB(bFb, BK);
        PACKB(Bs0, bFa);
        asm volatile("s_waitcnt vmcnt(2) lgkmcnt(0)" ::: "memory");
        __builtin_amdgcn_s_barrier();

        for (int t = 0; t < nt; t += 2) {
            {
                ISSUEA(As1, Bs1, (t + 1) * BK);
                __builtin_amdgcn_sched_barrier(0);
                const bool pf = (t + 2 < nt);
                if (pf) LOADB(bFa, (t + 2) * BK);
                COMPUTE(As0, Bs0);
                PACKB(Bs1, bFb);
                if (pf) asm volatile("s_waitcnt vmcnt(2) lgkmcnt(0)" ::: "memory");
                else    asm volatile("s_waitcnt vmcnt(0) lgkmcnt(0)" ::: "memory");
                __builtin_amdgcn_s_barrier();
            }
            {
                const bool p2 = (t + 2 < nt);
                const bool p3 = (t + 3 < nt);
                if (p2) ISSUEA(As0, Bs0, (t + 2) * BK);
                __builtin_amdgcn_sched_barrier(0);
                if (p3) LOADB(bFb, (t + 3) * BK);
                COMPUTE(As1, Bs1);
                if (p2) PACKB(Bs0, bFa);
                if (p3) asm volatile("s_waitcnt vmcnt(2) lgkmcnt(0)" ::: "memory");
                else    asm volatile("s_waitcnt vmcnt(0) lgkmcnt(0)" ::: "memory");
                __builtin_amdgcn_s_barrier();
            }
        }
    }

    #pragma unroll
    for (int mi = 0; mi < MI; ++mi) {
        #pragma unroll
        for (int ni = 0; ni < NI; ++ni) {
            const int n = n0 + wn * WNT + ni * 16 + (lane & 15);
            if (NBND && !PADW && n >= Ndim) continue;
            const int mbase = m0 + wm * WMT + mi * 16 + (lane >> 4) * 4;
            if constexpr (CT) {
                short4v sv;
                #pragma unroll
                for (int r = 0; r < 4; ++r) sv[r] = f2bf(acc[mi][ni][r]);
                *reinterpret_cast<short4v*>(&C[(size_t)n * ldc + mbase]) = sv;
            } else {
                #pragma unroll
                for (int r = 0; r < 4; ++r) {
                    float v = acc[mi][ni][r];
                    if (EPI == 1)      v = v / (1.f + __expf(-v));   // silu
                    else if (EPI == 2) v = v * aux[mbase + r];       // crcp
                    if constexpr (sizeof(TC) == 2) C[(size_t)(mbase + r) * ldc + n] = f2bf(v);
                    else                           C[(size_t)(mbase + r) * ldc + n] = v;
                }
            }
        }
    }
}

// ---------------- named GEMM wrappers (round-8 tiles/grids) ----------------
__global__ __launch_bounds__(256) void g1_gemm(const short* A, const short* B, short* C) {
    gemm_body<128, 128, 0, false, false, true, false, false, 0, short, short>(
        A, B, C, HID, 2048, BS, BS, HID, 2048L, 2048L, (long)ES * HID, nullptr);
}
__global__ __launch_bounds__(256) void g1f_gemm(const short* A, const float* B, short* C) {
    gemm_body<128, 64, 0, false, false, false, false, false, 4, float, short>(
        A, B, C, HID, 2048, BS, HID, HID, 2048L, 2048L * HID, (long)ES * HID, nullptr);
}
__global__ __launch_bounds__(256) void g2_gemm(const short* A, const float* B, short* C) {
    gemm_body<128, 64, 1, true, false, false, false, true, 4, float, short>(
        A, B, C, FFN, HID, HID, FFN, FFNP,
        (long)SLOT * HID, (long)HID * FFN, (long)SLOT * FFNP, nullptr);
}
__global__ __launch_bounds__(256) void g3_gemm(const short* A, const float* B, short* C) {
    gemm_body<64, 64, 0, false, true, false, true, false, 4, float, short>(
        A, B, C, HID, FFN, FFNP, HID, ES,
        (long)SLOT * FFNP, (long)FFN * HID, (long)SLOT, nullptr);
}
__global__ __launch_bounds__(256) void g4_gemm(const short* A, const short* B, float* C,
                                               const float* crcp) {
    gemm_body<128, 128, 2, false, false, true, false, false, 0, short, float>(
        A, B, C, HID, ES, ES, ES, HID, 0, 0, 0, crcp);
}

// ---------------- launch ----------------

extern "C" void kernel_launch(void* const* d_in, const int* in_sizes, int n_in,
                              void* d_out, int out_size, void* d_ws, size_t ws_size,
                              hipStream_t stream)
{
    const float* x      = (const float*)d_in[0];
    const float* logits = (const float*)d_in[1];   // [BS][ES]
    const float* w_up   = (const float*)d_in[2];   // [16][1024][2730]
    const float* w_down = (const float*)d_in[3];   // [16][2730][1024]
    float* y = (float*)d_out;

    float* wsf     = (float*)d_ws;
    float* drcp    = wsf;                               // 4*2048
    float* crcp    = wsf + 8192;                        // 8192
    float* rowpart = wsf + 16384;                       // 8192*32
    float* colpart = rowpart + (size_t)8192 * 32;       // 32*2048
    short* DT      = (short*)(colpart + (size_t)32 * 2048);  // [2048][8192] bf16
    short* CB      = DT + (size_t)ES * BS;              // [8192][2048] bf16
    short* part    = CB + (size_t)BS * ES;              // [4][2048][1024] bf16
    short* xt      = part + (size_t)4 * ES * HID;       // [2048][1024] bf16
    short* h       = xt + (size_t)ES * HID;             // [16][128][2752] bf16
    short* eoutT   = h + (size_t)NEXP * SLOT * FFNP;    // [1024][2048] bf16
    short* xT      = eoutT + (size_t)HID * ES;          // [1024][8192] bf16
    const size_t need_full = (size_t)((char*)(xT + (size_t)HID * BS) - (char*)d_ws);
    const bool use_bt = ws_size >= need_full;

    // NOTE: no memset. h pad columns (2730..2751) written as exact zeros by g2 (PADW).

    exp_stats_kernel<<<1024, 256, 0, stream>>>(logits, DT, CB, rowpart, colpart);
    rrow_kernel<<<32, 256, 0, stream>>>(rowpart, crcp);
    rcol_kernel<<<32, 256, 0, stream>>>(colpart, drcp);

    // G1: part[z] = expDT[:, batch z] @ x[batch z]   (K-split = batch x4, nt=64 -> 32 macro)
    if (use_bt) {
        transpose_x<<<dim3(128, 16, 1), 256, 0, stream>>>(x, xT);
        g1_gemm<<<dim3(16, 8, 4), 256, 0, stream>>>(DT, xT, part);
    } else {
        g1f_gemm<<<dim3(16, 16, 4), 256, 0, stream>>>(DT, x, part);
    }

    // xt = bf16(sum_z drcp[z] * part[z])
    reduce_xt<<<2048, 256, 0, stream>>>(part, drcp, xt);

    // G2: h[e] = silu(xt_e @ w_up_e), pad cols written as 0   (nt=32, f32x4 B loads)
    g2_gemm<<<dim3(1, 43, NEXP), 256, 0, stream>>>(xt, w_up, h);

    // G3: eoutT = (h_e @ w_down_e)^T   (nt=86, f32x4 B loads)
    g3_gemm<<<dim3(2, 16, NEXP), 256, 0, stream>>>(h, w_down, eoutT);

    // G4: y = expCB @ eout, row-scaled by crcp   (nt=64 -> 32 macro)
    g4_gemm<<<dim3(64, 8, 1), 256, 0, stream>>>(CB, eoutT, y, crcp);
}

// Round 18
// 284.090 us; speedup vs baseline: 1.0290x; 1.0127x over previous
//
#include <hip/hip_runtime.h>
#include <hip/hip_bf16.h>
#include <math.h>

#define BS   8192   // batch*seq tokens
#define SEQQ 2048
#define HID  1024
#define ES   2048   // n_exp * slots
#define FFN  2730
#define FFNP 2752   // FFN padded to multiple of 32
#define NEXP 16
#define SLOT 128

typedef __attribute__((ext_vector_type(4))) float  f32x4;
typedef __attribute__((ext_vector_type(2))) float  f32x2;
typedef __attribute__((ext_vector_type(8))) short  short8;
typedef __attribute__((ext_vector_type(4))) short  short4v;

__device__ __forceinline__ short f2bf(float f) {
    union { float f; unsigned u; } v; v.f = f;
    unsigned r = v.u + 0x7fffu + ((v.u >> 16) & 1u);   // RNE
    return (short)(r >> 16);
}

__device__ __forceinline__ float bf2f(short s) {
    union { unsigned u; float f; } v;
    v.u = ((unsigned)(unsigned short)s) << 16;
    return v.f;
}

// GEMM LDS swizzle (shorts). Row = 32 shorts, slot' = slot ^ ((row>>1)&3).
// Verified conflict-free for frag reads + 16B staging writes (rounds 4-17).
__device__ __forceinline__ int swz(int row, int kk) {
    return (row << 5) + ((((kk >> 3) ^ (row >> 1)) & 3) << 3) + (kk & 7);
}

// XCD-chunked bijective block swizzle (T1). HW round-robins dispatch index p
// onto XCD p%8; remap so each XCD handles a CONTIGUOUS logical chunk ->
// panel-sharing blocks co-reside on one XCD's L2. Requires nwg % 8 == 0.
__device__ __forceinline__ int xcdswz(int p, int nwg) {
    return (p & 7) * (nwg >> 3) + (p >> 3);
}

#define GLD16(gp, lp)                                                   \
    __builtin_amdgcn_global_load_lds(                                   \
        (__attribute__((address_space(1))) void*)(gp),                  \
        (__attribute__((address_space(3))) void*)(lp), 16, 0, 0)

// Transpose-tile swizzle for 64es x 256tok LDS tiles (see round 7).
__device__ __forceinline__ int tsw(int e) { return ((e >> 3) ^ e) & 7; }

// ---------- fused prep: exp(logits) -> DT [ES][BS] + CB [BS][ES] + sum partials ----------
__global__ __launch_bounds__(256) void exp_stats_kernel(const float* __restrict__ L,
                                                        short* __restrict__ DT,
                                                        short* __restrict__ CB,
                                                        float* __restrict__ rowpart,
                                                        float* __restrict__ colpart)
{
    const int t0 = (blockIdx.x & 31) << 8;       // 256-token tile
    const int et = blockIdx.x >> 5;              // es tile 0..31
    const int e0 = et << 6;                      // 64-es tile
    const int tid = threadIdx.x;
    const int lane = tid & 63;
    const int row = tid >> 3;                    // 0..31
    const int seg = tid & 7;                     // 0..7

    __shared__ short T[64 * 256];
    __shared__ float CP[4][64];

    float colacc[8];
    #pragma unroll
    for (int j = 0; j < 8; ++j) colacc[j] = 0.f;

    #pragma unroll
    for (int p = 0; p < 8; ++p) {
        const int tok = p * 32 + row;
        const float* src = L + (size_t)(t0 + tok) * ES + e0 + seg * 8;
        f32x4 a = *reinterpret_cast<const f32x4*>(src);
        f32x4 b = *reinterpret_cast<const f32x4*>(src + 4);
        float ex[8];
        #pragma unroll
        for (int j = 0; j < 4; ++j) ex[j]     = __expf(a[j]);
        #pragma unroll
        for (int j = 0; j < 4; ++j) ex[4 + j] = __expf(b[j]);
        float rs = 0.f;
        #pragma unroll
        for (int j = 0; j < 8; ++j) {
            const int e = seg * 8 + j;
            T[e * 256 + (tok ^ (((seg ^ j) & 7) << 3))] = f2bf(ex[j]);
            colacc[j] += ex[j];
            rs += ex[j];
        }
        rs += __shfl_xor(rs, 1, 64);
        rs += __shfl_xor(rs, 2, 64);
        rs += __shfl_xor(rs, 4, 64);
        if (seg == 0) rowpart[(size_t)(t0 + tok) * 32 + et] = rs;
    }
    #pragma unroll
    for (int j = 0; j < 8; ++j) {
        colacc[j] += __shfl_xor(colacc[j], 8, 64);
        colacc[j] += __shfl_xor(colacc[j], 16, 64);
        colacc[j] += __shfl_xor(colacc[j], 32, 64);
    }
    if ((lane >> 3) == 0) {
        #pragma unroll
        for (int j = 0; j < 8; ++j) CP[tid >> 6][(lane & 7) * 8 + j] = colacc[j];
    }
    __syncthreads();
    if (tid < 64)
        colpart[(size_t)(t0 >> 8) * ES + e0 + tid] =
            CP[0][tid] + CP[1][tid] + CP[2][tid] + CP[3][tid];
    // DT write-out (tok-contiguous 16B chunks per es row)
    {
        const int e = tid >> 2, ts = tid & 3;
        const int sw = tsw(e) << 3;
        const size_t o = (size_t)(e0 + e) * BS + t0 + ts * 64;
        #pragma unroll
        for (int q = 0; q < 8; ++q) {
            short8 w = *reinterpret_cast<const short8*>(&T[e * 256 + ((ts * 64 + q * 8) ^ sw)]);
            *reinterpret_cast<short8*>(&DT[o + q * 8]) = w;
        }
    }
    // CB write-out (es-contiguous 16B chunks per token)
    {
        #pragma unroll
        for (int p = 0; p < 8; ++p) {
            const int tok = p * 32 + row;
            short8 w;
            #pragma unroll
            for (int j = 0; j < 8; ++j) {
                const int e = seg * 8 + j;
                w[j] = T[e * 256 + (tok ^ (((seg ^ j) & 7) << 3))];
            }
            *reinterpret_cast<short8*>(&CB[(size_t)(t0 + tok) * ES + e0 + seg * 8]) = w;
        }
    }
}

// ---------- merged: crcp (blocks 0..31) + drcp (blocks 32..63) ----------
__global__ __launch_bounds__(256) void rstats_kernel(const float* __restrict__ rowpart,
                                                     const float* __restrict__ colpart,
                                                     float* __restrict__ crcp,
                                                     float* __restrict__ drcp)
{
    const int b = blockIdx.x;
    const int tid = threadIdx.x;
    if (b < 32) {
        const int t = b * 256 + tid;
        const float* p = rowpart + (size_t)t * 32;
        float s = 0.f;
        #pragma unroll
        for (int j = 0; j < 8; ++j) {
            f32x4 v = *reinterpret_cast<const f32x4*>(p + 4 * j);
            s += (v[0] + v[1]) + (v[2] + v[3]);
        }
        crcp[t] = 1.f / s;
    } else {
        const int g = (b - 32) * 256 + tid;   // bb*2048 + c
        const int bb = g >> 11, c = g & 2047;
        float s = 0.f;
        #pragma unroll
        for (int ch = 0; ch < 8; ++ch)
            s += colpart[(size_t)(bb * 8 + ch) * ES + c];
        drcp[g] = 1.f / s;
    }
}

// ---------- x fp32 [8192][1024] -> xT bf16 [1024][8192] ----------
__global__ __launch_bounds__(256) void transpose_x(const float* __restrict__ X,
                                                   short* __restrict__ XT)
{
    __shared__ short T[64][72];
    const int tid = threadIdx.x;
    const int k0 = blockIdx.x * 64;
    const int n0 = blockIdx.y * 64;
    {
        const int kk = tid >> 2;
        const int nn = (tid & 3) * 16;
        const float* src = X + (size_t)(k0 + kk) * HID + n0 + nn;
        #pragma unroll
        for (int j = 0; j < 4; ++j) {
            f32x4 v = *reinterpret_cast<const f32x4*>(src + 4 * j);
            short4v s;
            #pragma unroll
            for (int i = 0; i < 4; ++i) s[i] = f2bf(v[i]);
            *reinterpret_cast<short4v*>(&T[kk][nn + 4 * j]) = s;
        }
    }
    __syncthreads();
    {
        const int nn  = tid >> 2;
        const int kk4 = (tid & 3) * 16;
        short8 w0, w1;
        #pragma unroll
        for (int i = 0; i < 8; ++i) w0[i] = T[kk4 + i][nn];
        #pragma unroll
        for (int i = 0; i < 8; ++i) w1[i] = T[kk4 + 8 + i][nn];
        size_t o = (size_t)(n0 + nn) * BS + k0 + kk4;
        *reinterpret_cast<short8*>(&XT[o])     = w0;
        *reinterpret_cast<short8*>(&XT[o + 8]) = w1;
    }
}

// ---------- xt = bf16(sum_z drcp[z][c] * part_bf16[z][c][h]) (z = batch, 4 splits) ----------
__global__ __launch_bounds__(256) void reduce_xt(const short* __restrict__ P,
                                                 const float* __restrict__ drcp,
                                                 short* __restrict__ xt)
{
    const size_t i = ((size_t)blockIdx.x * 256 + threadIdx.x) * 4;
    const int c = (int)(i >> 10);
    const size_t CH = (size_t)ES * HID;
    short4v s0 = *reinterpret_cast<const short4v*>(&P[i]);
    short4v s1 = *reinterpret_cast<const short4v*>(&P[i + CH]);
    short4v s2 = *reinterpret_cast<const short4v*>(&P[i + 2 * CH]);
    short4v s3 = *reinterpret_cast<const short4v*>(&P[i + 3 * CH]);
    const float r0 = drcp[c], r1 = drcp[ES + c], r2 = drcp[2 * ES + c], r3 = drcp[3 * ES + c];
    short4v o;
    #pragma unroll
    for (int j = 0; j < 4; ++j)
        o[j] = f2bf((bf2f(s0[j]) * r0 + bf2f(s1[j]) * r1) +
                    (bf2f(s2[j]) * r2 + bf2f(s3[j]) * r3));
    *reinterpret_cast<short4v*>(&xt[i]) = o;
}

// ---------------- bf16 MFMA GEMM body (block coords passed in) ----------------
// BT path: gload_lds A+B dbuf with BK=64 macro-steps (round 17).
// float-B path (FW=4): f32x4 weight loads + counted-vmcnt raw barriers (round 14).
// EPI: 0 none, 1 silu, 2 row-scale by aux[m].
// PADW: store n >= Ndim too (acc==0 there since B staged 0).
template<int BM, int BN, int EPI, bool NBND, bool KBND, bool BT, bool CT, bool PADW,
         int FW, typename TB, typename TC>
__device__ __forceinline__
void gemm_body(const short* __restrict__ A, const TB* __restrict__ B,
               TC* __restrict__ C, int Ndim, int Kdim,
               int lda, int ldb, int ldc,
               long sA, long sB, long sC, const float* __restrict__ aux,
               int bx, int by, int bz)
{
    constexpr int BK = 32;
    constexpr int HB = BT ? 2 : 1;            // k-halves per buffer
    A += (size_t)bz * sA;
    B += (size_t)bz * sB;
    C += (size_t)bz * sC;
    const int m0 = bx * BM;
    const int n0 = by * BN;
    const int tid  = threadIdx.x;
    const int lane = tid & 63;
    const int wid  = tid >> 6;
    const int wm = wid >> 1, wn = wid & 1;
    constexpr int WMT = BM / 2, WNT = BN / 2, MI = WMT / 16, NI = WNT / 16;
    constexpr int PA = BM / 64;
    constexpr int PB = BN / 64;

    __shared__ __align__(16) short As0[BM * 32 * HB], As1[BM * 32 * HB];
    __shared__ __align__(16) short Bs0[BN * 32 * HB], Bs1[BN * 32 * HB];

    f32x4 acc[MI][NI];
    #pragma unroll
    for (int mi = 0; mi < MI; ++mi)
        #pragma unroll
        for (int ni = 0; ni < NI; ++ni)
            acc[mi][ni] = (f32x4){0.f, 0.f, 0.f, 0.f};

    // float-B lane geometry (FW==4): 4 n x 2 k per thread
    const int fn = (tid & 15) * 4;
    const int fk = (tid >> 4) * 2;

    // issue direct-to-LDS loads for one 32-k sub-tile of A (and B when BT)
    auto ISSUEA = [&](short* ASP, short* BSP, int kk) {
        #pragma unroll
        for (int p = 0; p < PA; ++p) {
            const int slot = p * 256 + tid;
            const int row  = slot >> 2;
            const int seg  = (slot & 3) ^ ((row >> 1) & 3);
            GLD16(&A[(size_t)(m0 + row) * lda + kk + seg * 8],
                  &ASP[(p * 256 + wid * 64) * 8]);
        }
        if constexpr (BT) {
            #pragma unroll
            for (int p = 0; p < PB; ++p) {
                const int slot = p * 256 + tid;
                const int row  = slot >> 2;
                const int seg  = (slot & 3) ^ ((row >> 1) & 3);
                GLD16(&B[(size_t)(n0 + row) * ldb + kk + seg * 8],
                      &BSP[(p * 256 + wid * 64) * 8]);
            }
        }
    };

    // float-B: 2x f32x4 into named regs. NBND tail: per-element guarded loads.
    auto LOADB = [&](f32x4* bF, int kk) {
        const int n_ = n0 + fn;
        #pragma unroll
        for (int r = 0; r < 2; ++r) {
            const int k_ = kk + fk + r;
            const bool okk = (!KBND) || (k_ < Kdim);
            if constexpr (NBND) {
                if (okk && (n_ + 3 < Ndim)) {
                    bF[r] = *reinterpret_cast<const f32x4*>(&B[(size_t)k_ * ldb + n_]);
                } else {
                    #pragma unroll
                    for (int i = 0; i < 4; ++i)
                        bF[r][i] = (okk && (n_ + i < Ndim))
                                       ? B[(size_t)k_ * ldb + n_ + i] : 0.f;
                }
            } else {
                bF[r] = okk ? *reinterpret_cast<const f32x4*>(&B[(size_t)k_ * ldb + n_])
                            : (f32x4){0.f, 0.f, 0.f, 0.f};
            }
        }
    };

    auto PACKB = [&](short* BSP, const f32x4* bF) {
        #pragma unroll
        for (int i = 0; i < 4; ++i) {
            unsigned lo = (unsigned short)f2bf(bF[0][i]);
            unsigned hi = (unsigned short)f2bf(bF[1][i]);
            *reinterpret_cast<unsigned*>(&BSP[swz(fn + i, fk)]) = lo | (hi << 16);
        }
    };

    auto COMPUTE = [&](const short* ASP, const short* BSP) {
        const int ar = lane & 15;
        const int ac = (lane >> 4) * 8;
        short8 af[MI], bf[NI];
        #pragma unroll
        for (int mi = 0; mi < MI; ++mi)
            af[mi] = *reinterpret_cast<const short8*>(&ASP[swz(wm * WMT + mi * 16 + ar, ac)]);
        #pragma unroll
        for (int ni = 0; ni < NI; ++ni)
            bf[ni] = *reinterpret_cast<const short8*>(&BSP[swz(wn * WNT + ni * 16 + ar, ac)]);
        #pragma unroll
        for (int mi = 0; mi < MI; ++mi)
            #pragma unroll
            for (int ni = 0; ni < NI; ++ni)
                acc[mi][ni] = __builtin_amdgcn_mfma_f32_16x16x32_bf16(
                    af[mi], bf[ni], acc[mi][ni], 0, 0, 0);
    };

    const int Kloop = KBND ? ((Kdim + 31) & ~31) : Kdim;
    const int nt = Kloop / BK;

    if constexpr (BT) {
        // BK=64 macro-steps (round 17): two 32-k sub-tiles per buffer/barrier.
        const int nt2 = nt / 2;
        auto ISSUE2 = [&](short* ASP, short* BSP, int T) {
            ISSUEA(ASP, BSP, T * 64);
            ISSUEA(ASP + BM * 32, BSP + BN * 32, T * 64 + 32);
        };
        auto COMPUTE2 = [&](const short* ASP, const short* BSP) {
            COMPUTE(ASP, BSP);
            COMPUTE(ASP + BM * 32, BSP + BN * 32);
        };
        ISSUE2(As0, Bs0, 0);
        __syncthreads();
        for (int t = 0; t < nt2; t += 2) {
            ISSUE2(As1, Bs1, t + 1);           // t+1 < nt2 (nt2 even)
            COMPUTE2(As0, Bs0);
            __syncthreads();
            const bool p2 = (t + 2 < nt2);
            if (p2) ISSUE2(As0, Bs0, t + 2);
            COMPUTE2(As1, Bs1);
            __syncthreads();
        }
    } else {
        // counted-vmcnt raw-barrier schedule (round 14).
        f32x4 bFa[2], bFb[2];
        LOADB(bFa, 0);
        __builtin_amdgcn_sched_barrier(0);
        ISSUEA(As0, Bs0, 0);
        __builtin_amdgcn_sched_barrier(0);
        LOADB(bFb, BK);
        PACKB(Bs0, bFa);
        asm volatile("s_waitcnt vmcnt(2) lgkmcnt(0)" ::: "memory");
        __builtin_amdgcn_s_barrier();

        for (int t = 0; t < nt; t += 2) {
            {
                ISSUEA(As1, Bs1, (t + 1) * BK);
                __builtin_amdgcn_sched_barrier(0);
                const bool pf = (t + 2 < nt);
                if (pf) LOADB(bFa, (t + 2) * BK);
                COMPUTE(As0, Bs0);
                PACKB(Bs1, bFb);
                if (pf) asm volatile("s_waitcnt vmcnt(2) lgkmcnt(0)" ::: "memory");
                else    asm volatile("s_waitcnt vmcnt(0) lgkmcnt(0)" ::: "memory");
                __builtin_amdgcn_s_barrier();
            }
            {
                const bool p2 = (t + 2 < nt);
                const bool p3 = (t + 3 < nt);
                if (p2) ISSUEA(As0, Bs0, (t + 2) * BK);
                __builtin_amdgcn_sched_barrier(0);
                if (p3) LOADB(bFb, (t + 3) * BK);
                COMPUTE(As1, Bs1);
                if (p2) PACKB(Bs0, bFa);
                if (p3) asm volatile("s_waitcnt vmcnt(2) lgkmcnt(0)" ::: "memory");
                else    asm volatile("s_waitcnt vmcnt(0) lgkmcnt(0)" ::: "memory");
                __builtin_amdgcn_s_barrier();
            }
        }
    }

    #pragma unroll
    for (int mi = 0; mi < MI; ++mi) {
        #pragma unroll
        for (int ni = 0; ni < NI; ++ni) {
            const int n = n0 + wn * WNT + ni * 16 + (lane & 15);
            if (NBND && !PADW && n >= Ndim) continue;
            const int mbase = m0 + wm * WMT + mi * 16 + (lane >> 4) * 4;
            if constexpr (CT) {
                short4v sv;
                #pragma unroll
                for (int r = 0; r < 4; ++r) sv[r] = f2bf(acc[mi][ni][r]);
                *reinterpret_cast<short4v*>(&C[(size_t)n * ldc + mbase]) = sv;
            } else {
                #pragma unroll
                for (int r = 0; r < 4; ++r) {
                    float v = acc[mi][ni][r];
                    if (EPI == 1)      v = v / (1.f + __expf(-v));   // silu
                    else if (EPI == 2) v = v * aux[mbase + r];       // crcp
                    if constexpr (sizeof(TC) == 2) C[(size_t)(mbase + r) * ldc + n] = f2bf(v);
                    else                           C[(size_t)(mbase + r) * ldc + n] = v;
                }
            }
        }
    }
}

// ---------------- named GEMM wrappers (1-D grids + XCD-chunked swizzle) ----------------
// g1: 512 blocks = 16m x 8n x 4z, logical order l = (z*8+n)*16 + m (m fastest:
//     consecutive l share the xT n-panel; chunk of 64 on one XCD).
__global__ __launch_bounds__(256) void g1_gemm(const short* A, const short* B, short* C) {
    const int l = xcdswz(blockIdx.x, 512);
    const int m = l & 15, rest = l >> 4, n = rest & 7, z = rest >> 3;
    gemm_body<128, 128, 0, false, false, true, false, false, 0, short, short>(
        A, B, C, HID, 2048, BS, BS, HID, 2048L, 2048L, (long)ES * HID, nullptr, m, n, z);
}
__global__ __launch_bounds__(256) void g1f_gemm(const short* A, const float* B, short* C) {
    gemm_body<128, 64, 0, false, false, false, false, false, 4, float, short>(
        A, B, C, HID, 2048, BS, HID, HID, 2048L, 2048L * HID, (long)ES * HID, nullptr,
        blockIdx.x, blockIdx.y, blockIdx.z);
}
// g2: 688 blocks = 43n x 16z, logical l = z*43 + n (expert-major: chunk of 86
//     = 2 experts per XCD -> xt_e A-panels L2-resident).
__global__ __launch_bounds__(256) void g2_gemm(const short* A, const float* B, short* C) {
    const int l = xcdswz(blockIdx.x, 688);
    const int z = l / 43, n = l % 43;
    gemm_body<128, 64, 1, true, false, false, false, true, 4, float, short>(
        A, B, C, FFN, HID, HID, FFN, FFNP,
        (long)SLOT * HID, (long)HID * FFN, (long)SLOT * FFNP, nullptr, 0, n, z);
}
// g3: 512 blocks = 2m x 16n x 16z, logical l = (z*16+n)*2 + m (h_e A-panels
//     reused by 16 n-blocks within the XCD chunk).
__global__ __launch_bounds__(256) void g3_gemm(const short* A, const float* B, short* C) {
    const int l = xcdswz(blockIdx.x, 512);
    const int m = l & 1, rest = l >> 1, n = rest & 15, z = rest >> 4;
    gemm_body<64, 64, 0, false, true, false, true, false, 4, float, short>(
        A, B, C, HID, FFN, FFNP, HID, ES,
        (long)SLOT * FFNP, (long)FFN * HID, (long)SLOT, nullptr, m, n, z);
}
// g4: 512 blocks = 64m x 8n, logical l = n*64 + m (m fastest: the eoutT
//     n-panel (512 KB) is reused by all 64 m-blocks of the chunk from L2).
__global__ __launch_bounds__(256) void g4_gemm(const short* A, const short* B, float* C,
                                               const float* crcp) {
    const int l = xcdswz(blockIdx.x, 512);
    const int m = l & 63, n = l >> 6;
    gemm_body<128, 128, 2, false, false, true, false, false, 0, short, float>(
        A, B, C, HID, ES, ES, ES, HID, 0, 0, 0, crcp, m, n, 0);
}

// ---------------- launch ----------------

extern "C" void kernel_launch(void* const* d_in, const int* in_sizes, int n_in,
                              void* d_out, int out_size, void* d_ws, size_t ws_size,
                              hipStream_t stream)
{
    const float* x      = (const float*)d_in[0];
    const float* logits = (const float*)d_in[1];   // [BS][ES]
    const float* w_up   = (const float*)d_in[2];   // [16][1024][2730]
    const float* w_down = (const float*)d_in[3];   // [16][2730][1024]
    float* y = (float*)d_out;

    float* wsf     = (float*)d_ws;
    float* drcp    = wsf;                               // 4*2048
    float* crcp    = wsf + 8192;                        // 8192
    float* rowpart = wsf + 16384;                       // 8192*32
    float* colpart = rowpart + (size_t)8192 * 32;       // 32*2048
    short* DT      = (short*)(colpart + (size_t)32 * 2048);  // [2048][8192] bf16
    short* CB      = DT + (size_t)ES * BS;              // [8192][2048] bf16
    short* part    = CB + (size_t)BS * ES;              // [4][2048][1024] bf16
    short* xt      = part + (size_t)4 * ES * HID;       // [2048][1024] bf16
    short* h       = xt + (size_t)ES * HID;             // [16][128][2752] bf16
    short* eoutT   = h + (size_t)NEXP * SLOT * FFNP;    // [1024][2048] bf16
    short* xT      = eoutT + (size_t)HID * ES;          // [1024][8192] bf16
    const size_t need_full = (size_t)((char*)(xT + (size_t)HID * BS) - (char*)d_ws);
    const bool use_bt = ws_size >= need_full;

    // NOTE: no memset. h pad columns (2730..2751) written as exact zeros by g2 (PADW).

    exp_stats_kernel<<<1024, 256, 0, stream>>>(logits, DT, CB, rowpart, colpart);
    rstats_kernel<<<64, 256, 0, stream>>>(rowpart, colpart, crcp, drcp);

    // G1: part[z] = expDT[:, batch z] @ x[batch z]   (K-split = batch x4, nt=64 -> 32 macro)
    if (use_bt) {
        transpose_x<<<dim3(128, 16, 1), 256, 0, stream>>>(x, xT);
        g1_gemm<<<512, 256, 0, stream>>>(DT, xT, part);
    } else {
        g1f_gemm<<<dim3(16, 16, 4), 256, 0, stream>>>(DT, x, part);
    }

    // xt = bf16(sum_z drcp[z] * part[z])
    reduce_xt<<<2048, 256, 0, stream>>>(part, drcp, xt);

    // G2: h[e] = silu(xt_e @ w_up_e), pad cols written as 0   (nt=32, f32x4 B loads)
    g2_gemm<<<688, 256, 0, stream>>>(xt, w_up, h);

    // G3: eoutT = (h_e @ w_down_e)^T   (nt=86, f32x4 B loads)
    g3_gemm<<<512, 256, 0, stream>>>(h, w_down, eoutT);

    // G4: y = expCB @ eout, row-scaled by crcp   (nt=64 -> 32 macro)
    g4_gemm<<<512, 256, 0, stream>>>(CB, eoutT, y, crcp);
}